// Round 16
// baseline (609.598 us; speedup 1.0000x reference)
//
#include <hip/hip_runtime.h>
#include <hip/hip_bf16.h>
#include <math.h>

// Problem constants (fixed by the reference)
#define NN     100000   // nodes
#define GG     2000     // graphs
#define HH     4        // heads
#define DD     64       // per-head dim
#define HID    256      // H*D
#define INF_   64       // in feats
#define EXTRA  8        // graph feats

typedef unsigned short u16;
typedef __attribute__((ext_vector_type(8))) short bf16x8;
typedef __attribute__((ext_vector_type(4))) float f32x4;

__device__ __forceinline__ u16 f2bf(float f) {
    unsigned u = __float_as_uint(f);
    return (u16)((u + 0x7fffu + ((u >> 16) & 1u)) >> 16);
}
__device__ __forceinline__ float bf2f(u16 v) {
    return __uint_as_float(((unsigned)v) << 16);
}

// ---------------- W [K,256] -> FRAGMENT-ORDERED hi/lo bf16 --------------------
// Layout: [(n>>4)][(k>>3)][n&15][k&7] -> a wave's MFMA B-fragment load is
// 16 lanes x 16B = coalesced 256B, straight from global/L2 (no LDS, no
// barrier dependency). Values identical to the old transposed layout.
__global__ __launch_bounds__(256) void wsplit_kernel(
    const float* __restrict__ W, u16* __restrict__ hi, u16* __restrict__ lo,
    int K, int lgK)
{
    int idx = blockIdx.x * 256 + threadIdx.x;   // n*K + k
    if (idx >= 256 * K) return;
    int n = idx >> lgK, k = idx & (K - 1);
    float w = W[k * HID + n];
    u16 h = f2bf(w);
    int off = (((n >> 4) * (K >> 3) + (k >> 3)) << 7) + ((n & 15) << 3) + (k & 7);
    hi[off] = h;
    lo[off] = f2bf(w - bf2f(h));
}

// ---------------- wal/war precompute: wal[d][h] = sum_c W1[d][h*64+c]*al[h][c]
__global__ __launch_bounds__(256) void walprep_kernel(
    const float* __restrict__ W1, const float* __restrict__ al,
    const float* __restrict__ ar, float* __restrict__ wal, float* __restrict__ war)
{
    int tid = threadIdx.x;          // 256 = 64 d x 4 h
    int d = tid >> 2, h = tid & 3;
    const float* wrow = W1 + d * HID + h * DD;
    const float* av = al + h * DD;
    const float* bv = ar + h * DD;
    float s1 = 0.f, s2 = 0.f;
    for (int c = 0; c < DD; ++c) { s1 += wrow[c] * av[c]; s2 += wrow[c] * bv[c]; }
    wal[d * 4 + h] = s1;
    war[d * 4 + h] = s2;
}

// ---------------- el1/er1 from raw feats (reassociated: feats @ wal1) ---------
__global__ __launch_bounds__(256) void elr1_kernel(
    const float* __restrict__ feats, const float* __restrict__ wal,
    const float* __restrict__ war, float* __restrict__ el, float* __restrict__ er)
{
    int idx = blockIdx.x * 256 + threadIdx.x;   // (n,h)
    if (idx >= NN * HH) return;
    int n = idx >> 2, h = idx & 3;
    const float* f = feats + (size_t)n * INF_;
    float s1 = 0.f, s2 = 0.f;
    #pragma unroll 4
    for (int d = 0; d < INF_; d += 4) {
        float4 fv = *reinterpret_cast<const float4*>(f + d);
        s1 += fv.x * wal[(d + 0) * 4 + h] + fv.y * wal[(d + 1) * 4 + h]
            + fv.z * wal[(d + 2) * 4 + h] + fv.w * wal[(d + 3) * 4 + h];
        s2 += fv.x * war[(d + 0) * 4 + h] + fv.y * war[(d + 1) * 4 + h]
            + fv.z * war[(d + 2) * 4 + h] + fv.w * war[(d + 3) * 4 + h];
    }
    el[idx] = s1;
    er[idx] = s2;
}

__device__ __forceinline__ float leaky02(float x) { return x > 0.f ? x : 0.2f * x; }

// ---------------- edge softmax: one thread per (dst-node, head) ---------------
// SEPARATE kernel (round-14 lesson: VALU time is per-wave, not per-active-
// lane; fusing into the wave-per-node aggregate cost 16x more exp work).
__global__ __launch_bounds__(256) void edge_softmax_kernel(
    const float* __restrict__ el, const float* __restrict__ er,
    const int* __restrict__ rowptr, const int* __restrict__ colsrc,
    float* __restrict__ w, float* __restrict__ invden)
{
    int idx = blockIdx.x * 256 + threadIdx.x;   // (t,h)
    if (idx >= NN * HH) return;
    int t = idx >> 2, h = idx & 3;
    int beg = rowptr[t], end = rowptr[t + 1];
    float ert = er[idx];
    float m = -1e30f;
    for (int i = beg; i < end; ++i) {
        int s = colsrc[i];
        m = fmaxf(m, leaky02(el[s * 4 + h] + ert));
    }
    float den = 0.f;
    for (int i = beg; i < end; ++i) {
        int s = colsrc[i];
        float v = expf(leaky02(el[s * 4 + h] + ert) - m);
        w[(size_t)i * 4 + h] = v;
        den += v;
    }
    invden[idx] = 1.f / den;   // deg >= 1 (self-loops), den > 0
}

// ---------------- layer-1 aggregate over RAW feats -> PRE-SPLIT Y1 ------------
__global__ __launch_bounds__(256) void aggregate_feats_kernel(
    const float* __restrict__ feats, const float* __restrict__ w,
    const float* __restrict__ invden, const int* __restrict__ rowptr,
    const int* __restrict__ colsrc, u16* __restrict__ Yh, u16* __restrict__ Yl)
{
    int t = blockIdx.x * 4 + (threadIdx.x >> 6);
    int lane = threadIdx.x & 63;
    if (t >= NN) return;
    int beg = rowptr[t], end = rowptr[t + 1];
    float a0 = 0.f, a1 = 0.f, a2 = 0.f, a3 = 0.f;
    float b0 = 0.f, b1 = 0.f, b2 = 0.f, b3 = 0.f;
    int i = beg;
    for (; i + 1 < end; i += 2) {
        int s0 = colsrc[i], s1 = colsrc[i + 1];
        float4 w0 = *reinterpret_cast<const float4*>(w + (size_t)i * 4);
        float4 w1 = *reinterpret_cast<const float4*>(w + (size_t)(i + 1) * 4);
        float f0 = feats[(size_t)s0 * INF_ + lane];
        float f1 = feats[(size_t)s1 * INF_ + lane];
        a0 += w0.x * f0; a1 += w0.y * f0; a2 += w0.z * f0; a3 += w0.w * f0;
        b0 += w1.x * f1; b1 += w1.y * f1; b2 += w1.z * f1; b3 += w1.w * f1;
    }
    if (i < end) {
        int s0 = colsrc[i];
        float4 w0 = *reinterpret_cast<const float4*>(w + (size_t)i * 4);
        float f0 = feats[(size_t)s0 * INF_ + lane];
        a0 += w0.x * f0; a1 += w0.y * f0; a2 += w0.z * f0; a3 += w0.w * f0;
    }
    float4 inv = *reinterpret_cast<const float4*>(invden + (size_t)t * 4);
    float y0 = (a0 + b0) * inv.x;
    float y1 = (a1 + b1) * inv.y;
    float y2 = (a2 + b2) * inv.z;
    float y3 = (a3 + b3) * inv.w;
    u16* yh = Yh + (size_t)t * HID;
    u16* yl = Yl + (size_t)t * HID;
    u16 h0 = f2bf(y0), h1 = f2bf(y1), h2 = f2bf(y2), h3 = f2bf(y3);
    yh[lane] = h0;        yl[lane] = f2bf(y0 - bf2f(h0));
    yh[64 + lane] = h1;   yl[64 + lane] = f2bf(y1 - bf2f(h1));
    yh[128 + lane] = h2;  yl[128 + lane] = f2bf(y2 - bf2f(h2));
    yh[192 + lane] = h3;  yl[192 + lane] = f2bf(y3 - bf2f(h3));
}

// ---------------- per-head GEMM: X1 = relu(Y1 @ W1 + b1) ----------------------
// A staged in swizzled LDS; B loaded DIRECT from fragment-ordered global
// (coalesced 256B per fragment, L2-hot 64KB, no barrier dependency).
__global__ __launch_bounds__(256) void gemm_head_kernel(
    const u16* __restrict__ Yh, const u16* __restrict__ Yl,
    const u16* __restrict__ BThi, const u16* __restrict__ BTlo,
    const float* __restrict__ bias,
    u16* __restrict__ Xh, u16* __restrict__ Xl, int M)
{
    __shared__ __align__(16) u16 Ah[128 * 64];
    __shared__ __align__(16) u16 Al[128 * 64];
    const int tid  = threadIdx.x;
    const int wave = tid >> 6, lane = tid & 63;
    const int quad = lane >> 4, l15 = lane & 15;
    const int wy = wave >> 1, wx = wave & 1;      // 2x2: 64 rows x 32 cols each
    const int head = blockIdx.y;
    const int r0 = blockIdx.x * 128;
    const int cb = head * DD;                      // this head's Y1 column base

    // ---- stage A: 128 rows x 64 k (hi+lo), thread = (row, half32) ----
    {
        int row = tid >> 1, half = tid & 1;
        int gr = min(r0 + row, M - 1);
        size_t goff = (size_t)gr * HID + cb;
        #pragma unroll
        for (int m = 0; m < 4; ++m) {
            int c = half * 4 + m;                  // global chunk (8 u16)
            int cs = c ^ (row & 7);                // swizzled LDS chunk
            *reinterpret_cast<bf16x8*>(&Ah[row * 64 + cs * 8]) =
                *reinterpret_cast<const bf16x8*>(Yh + goff + c * 8);
            *reinterpret_cast<bf16x8*>(&Al[row * 64 + cs * 8]) =
                *reinterpret_cast<const bf16x8*>(Yl + goff + c * 8);
        }
    }
    __syncthreads();

    f32x4 acc[4][2];
    #pragma unroll
    for (int i = 0; i < 4; ++i)
        #pragma unroll
        for (int j = 0; j < 2; ++j)
            acc[i][j] = (f32x4){0.f, 0.f, 0.f, 0.f};

    #pragma unroll
    for (int k0 = 0; k0 < 64; k0 += 32) {
        bf16x8 afh[4], afl[4], bfh[2], bfl[2];
        #pragma unroll
        for (int j = 0; j < 2; ++j) {
            int nb = head * 4 + wx * 2 + j;        // global 16-col block index
            int kc = (k0 >> 3) + quad;
            size_t off = ((size_t)(nb * 8 + kc) << 7) + (l15 << 3);  // K=64: K>>3=8
            bfh[j] = *reinterpret_cast<const bf16x8*>(BThi + off);
            bfl[j] = *reinterpret_cast<const bf16x8*>(BTlo + off);
        }
        #pragma unroll
        for (int i = 0; i < 4; ++i) {
            int Ra = wy * 64 + i * 16 + l15;
            int c = (k0 >> 3) + quad;
            int cs = c ^ (Ra & 7);
            afh[i] = *reinterpret_cast<const bf16x8*>(&Ah[Ra * 64 + cs * 8]);
            afl[i] = *reinterpret_cast<const bf16x8*>(&Al[Ra * 64 + cs * 8]);
        }
        #pragma unroll
        for (int i = 0; i < 4; ++i)
            #pragma unroll
            for (int j = 0; j < 2; ++j) {
                acc[i][j] = __builtin_amdgcn_mfma_f32_16x16x32_bf16(afh[i], bfh[j], acc[i][j], 0, 0, 0);
                acc[i][j] = __builtin_amdgcn_mfma_f32_16x16x32_bf16(afl[i], bfh[j], acc[i][j], 0, 0, 0);
                acc[i][j] = __builtin_amdgcn_mfma_f32_16x16x32_bf16(afh[i], bfl[j], acc[i][j], 0, 0, 0);
            }
    }

    // ---- epilogue: bias + relu + split store. col = cb + wx*32 + j*16 + l15
    float bv[2];
    #pragma unroll
    for (int j = 0; j < 2; ++j) bv[j] = bias[cb + wx * 32 + j * 16 + l15];
    #pragma unroll
    for (int i = 0; i < 4; ++i)
        #pragma unroll
        for (int rr = 0; rr < 4; ++rr) {
            int grow = r0 + wy * 64 + i * 16 + quad * 4 + rr;
            if (grow < M) {
                size_t base = (size_t)grow * HID + cb + wx * 32 + l15;
                #pragma unroll
                for (int j = 0; j < 2; ++j) {
                    float x = fmaxf(acc[i][j][rr] + bv[j], 0.f);
                    u16 h = f2bf(x);
                    Xh[base + j * 16] = h;
                    Xl[base + j * 16] = f2bf(x - bf2f(h));
                }
            }
        }
}

// ---------------- MFMA GEMM (layer 2): LDS A (swizzled), global frag B --------
// LDS halved to A-only (16KB): per-k-tile LDS ~144cyc < MFMA 230cyc -> MFMA
// becomes the critical pipe (round 15: B through LDS made LDS the bottleneck
// at 288cyc). B frags are coalesced 256B global loads, L2-resident 256KB,
// prefetchable across k-iterations (no barrier dependency).
__global__ __launch_bounds__(256) void mfma_gemm_kernel(
    const u16* __restrict__ Ahg, const u16* __restrict__ Alg,
    const u16* __restrict__ BThi, const u16* __restrict__ BTlo,
    u16* __restrict__ Cb,
    const float* __restrict__ al, const float* __restrict__ ar,
    float* __restrict__ el, float* __restrict__ er, int M, int K)
{
    __shared__ __align__(16) u16 Ah[128 * 32];
    __shared__ __align__(16) u16 Al[128 * 32];
    const int tid  = threadIdx.x;
    const int wave = tid >> 6, lane = tid & 63;
    const int quad = lane >> 4, l15 = lane & 15;
    const int wy = wave >> 1, wx = wave & 1;
    const int r0 = blockIdx.x * 128, c0 = blockIdx.y * 128;
    const int sr = tid >> 2, sseg = tid & 3;

    f32x4 acc[4][4];
    #pragma unroll
    for (int i = 0; i < 4; ++i)
        #pragma unroll
        for (int j = 0; j < 4; ++j)
            acc[i][j] = (f32x4){0.f, 0.f, 0.f, 0.f};

    const int Kc = K >> 3;   // k-chunks per row
    for (int k0 = 0; k0 < K; k0 += 32) {
        #pragma unroll
        for (int half = 0; half < 2; ++half) {
            int r = sr + half * 64;
            int cs = (sseg ^ ((r >> 1) & 3)) * 8;  // swizzled LDS chunk offset
            int gr = min(r0 + r, M - 1);
            size_t aoff = (size_t)gr * K + k0 + sseg * 8;
            *reinterpret_cast<bf16x8*>(&Ah[r * 32 + cs]) =
                *reinterpret_cast<const bf16x8*>(Ahg + aoff);
            *reinterpret_cast<bf16x8*>(&Al[r * 32 + cs]) =
                *reinterpret_cast<const bf16x8*>(Alg + aoff);
        }
        __syncthreads();
        bf16x8 afh[4], afl[4], bfh[4], bfl[4];
        #pragma unroll
        for (int j = 0; j < 4; ++j) {
            int nb = (c0 + wx * 64 + j * 16) >> 4;
            int kc = (k0 >> 3) + quad;
            size_t off = ((size_t)(nb * Kc + kc) << 7) + (l15 << 3);
            bfh[j] = *reinterpret_cast<const bf16x8*>(BThi + off);
            bfl[j] = *reinterpret_cast<const bf16x8*>(BTlo + off);
        }
        #pragma unroll
        for (int i = 0; i < 4; ++i) {
            int Ra = wy * 64 + i * 16 + l15;
            int off = Ra * 32 + (quad ^ ((Ra >> 1) & 3)) * 8;
            afh[i] = *reinterpret_cast<const bf16x8*>(&Ah[off]);
            afl[i] = *reinterpret_cast<const bf16x8*>(&Al[off]);
        }
        #pragma unroll
        for (int i = 0; i < 4; ++i)
            #pragma unroll
            for (int j = 0; j < 4; ++j) {
                acc[i][j] = __builtin_amdgcn_mfma_f32_16x16x32_bf16(afh[i], bfh[j], acc[i][j], 0, 0, 0);
                acc[i][j] = __builtin_amdgcn_mfma_f32_16x16x32_bf16(afl[i], bfh[j], acc[i][j], 0, 0, 0);
                acc[i][j] = __builtin_amdgcn_mfma_f32_16x16x32_bf16(afh[i], bfl[j], acc[i][j], 0, 0, 0);
            }
        __syncthreads();
    }

    // ---- C store (bf16). C/D layout: col = l15, row = quad*4 + rr ----
    #pragma unroll
    for (int i = 0; i < 4; ++i)
        #pragma unroll
        for (int rr = 0; rr < 4; ++rr) {
            int grow = r0 + wy * 64 + i * 16 + quad * 4 + rr;
            if (grow < M) {
                u16* crow = Cb + (size_t)grow * HID + c0 + wx * 64 + l15;
                #pragma unroll
                for (int j = 0; j < 4; ++j) crow[j * 16] = f2bf(acc[i][j][rr]);
            }
        }

    // ---- fused el/er from f32 accumulators (one head per wave) ----
    const int h = blockIdx.y * 2 + wx;
    float alf[4], arf[4];
    #pragma unroll
    for (int j = 0; j < 4; ++j) {
        alf[j] = al[h * DD + j * 16 + l15];
        arf[j] = ar[h * DD + j * 16 + l15];
    }
    #pragma unroll
    for (int i = 0; i < 4; ++i)
        #pragma unroll
        for (int rr = 0; rr < 4; ++rr) {
            float sl = acc[i][0][rr] * alf[0] + acc[i][1][rr] * alf[1]
                     + acc[i][2][rr] * alf[2] + acc[i][3][rr] * alf[3];
            float sr_ = acc[i][0][rr] * arf[0] + acc[i][1][rr] * arf[1]
                      + acc[i][2][rr] * arf[2] + acc[i][3][rr] * arf[3];
            #pragma unroll
            for (int off = 1; off < 16; off <<= 1) {
                sl  += __shfl_xor(sl, off, 64);
                sr_ += __shfl_xor(sr_, off, 64);
            }
            if (l15 == 0) {
                int grow = r0 + wy * 64 + i * 16 + quad * 4 + rr;
                if (grow < M) {
                    el[grow * 4 + h] = sl;
                    er[grow * 4 + h] = sr_;
                }
            }
        }
}

// ---------------- layer-2 aggregate: bf16 gather -> bf16 out (pure gather) ----
__global__ __launch_bounds__(256) void aggregate_bf16_kernel(
    const u16* __restrict__ F, const float* __restrict__ w,
    const float* __restrict__ invden, const int* __restrict__ rowptr,
    const int* __restrict__ colsrc, const float* __restrict__ bias,
    u16* __restrict__ out)
{
    int t = blockIdx.x * 4 + (threadIdx.x >> 6);
    int lane = threadIdx.x & 63;
    if (t >= NN) return;
    int beg = rowptr[t], end = rowptr[t + 1];
    const int h = lane >> 4;
    float4 acc0 = make_float4(0.f, 0.f, 0.f, 0.f);
    float4 acc1 = make_float4(0.f, 0.f, 0.f, 0.f);
    int i = beg;
    for (; i + 1 < end; i += 2) {
        int s0 = colsrc[i], s1 = colsrc[i + 1];
        float w0 = w[(size_t)i * 4 + h];
        float w1 = w[(size_t)(i + 1) * 4 + h];
        ushort4 f0 = *reinterpret_cast<const ushort4*>(F + (size_t)s0 * HID + 4 * lane);
        ushort4 f1 = *reinterpret_cast<const ushort4*>(F + (size_t)s1 * HID + 4 * lane);
        acc0.x += w0 * bf2f(f0.x); acc0.y += w0 * bf2f(f0.y);
        acc0.z += w0 * bf2f(f0.z); acc0.w += w0 * bf2f(f0.w);
        acc1.x += w1 * bf2f(f1.x); acc1.y += w1 * bf2f(f1.y);
        acc1.z += w1 * bf2f(f1.z); acc1.w += w1 * bf2f(f1.w);
    }
    if (i < end) {
        int s0 = colsrc[i];
        float w0 = w[(size_t)i * 4 + h];
        ushort4 f0 = *reinterpret_cast<const ushort4*>(F + (size_t)s0 * HID + 4 * lane);
        acc0.x += w0 * bf2f(f0.x); acc0.y += w0 * bf2f(f0.y);
        acc0.z += w0 * bf2f(f0.z); acc0.w += w0 * bf2f(f0.w);
    }
    float inv = invden[t * 4 + h];
    float4 bv = *reinterpret_cast<const float4*>(bias + 4 * lane);
    ushort4 r;
    r.x = f2bf(fmaxf((acc0.x + acc1.x) * inv + bv.x, 0.f));
    r.y = f2bf(fmaxf((acc0.y + acc1.y) * inv + bv.y, 0.f));
    r.z = f2bf(fmaxf((acc0.z + acc1.z) * inv + bv.z, 0.f));
    r.w = f2bf(fmaxf((acc0.w + acc1.w) * inv + bv.w, 0.f));
    *reinterpret_cast<ushort4*>(out + (size_t)t * HID + 4 * lane) = r;
}

// ---------------- weighted-average readout (bf16 X): one wave per graph -------
__global__ __launch_bounds__(256) void readout_kernel(
    const u16* __restrict__ X, const float* __restrict__ Ws,
    const float* __restrict__ bs, const int* __restrict__ gptr,
    float* __restrict__ emb)
{
    int g = blockIdx.x * 4 + (threadIdx.x >> 6);
    int lane = threadIdx.x & 63;
    if (g >= GG) return;
    int beg = gptr[g], end = gptr[g + 1];
    float4 wv = *reinterpret_cast<const float4*>(Ws + 4 * lane);
    float b = bs[0];
    float4 acc = make_float4(0.f, 0.f, 0.f, 0.f);
    float wsum = 0.f;
    for (int n = beg; n < end; ++n) {
        ushort4 xv = *reinterpret_cast<const ushort4*>(X + (size_t)n * HID + 4 * lane);
        float x0 = bf2f(xv.x), x1 = bf2f(xv.y), x2 = bf2f(xv.z), x3 = bf2f(xv.w);
        float p = x0 * wv.x + x1 * wv.y + x2 * wv.z + x3 * wv.w;
        #pragma unroll
        for (int off = 32; off; off >>= 1) p += __shfl_xor(p, off, 64);
        float w = 1.f / (1.f + expf(-(p + b)));
        wsum += w;
        acc.x += w * x0; acc.y += w * x1; acc.z += w * x2; acc.w += w * x3;
    }
    float inv = (wsum == 0.f) ? 1.f : wsum;
    float4 e;
    e.x = acc.x / inv; e.y = acc.y / inv; e.z = acc.z / inv; e.w = acc.w / inv;
    *reinterpret_cast<float4*>(emb + (size_t)g * HID + 4 * lane) = e;
}

__device__ __forceinline__ float selu_f(float x)
{
    const float scale = 1.0507009873554805f, alpha = 1.6732632423543772f;
    return scale * (x > 0.f ? x : alpha * expm1f(x));
}

// ---------------- MLP head: one block (128 thr) per graph ----------------
__global__ __launch_bounds__(128) void mlp_kernel(
    const float* __restrict__ emb, const float* __restrict__ fg,
    const float* __restrict__ Wm1, const float* __restrict__ bm1,
    const float* __restrict__ Wm2, const float* __restrict__ bm2,
    const float* __restrict__ Wm3, const float* __restrict__ bm3,
    float* __restrict__ out)
{
    int g = blockIdx.x;
    __shared__ float h[HID + EXTRA];
    __shared__ float h1[128];
    __shared__ float h2[64];
    int tid = threadIdx.x;
    h[tid] = emb[(size_t)g * HID + tid];
    h[128 + tid] = emb[(size_t)g * HID + 128 + tid];
    if (tid < EXTRA) h[HID + tid] = fg[(size_t)g * EXTRA + tid];
    __syncthreads();
    float acc = bm1[tid];
    for (int i = 0; i < HID + EXTRA; ++i) acc += h[i] * Wm1[i * 128 + tid];
    h1[tid] = selu_f(acc);
    __syncthreads();
    if (tid < 64) {
        float acc2 = bm2[tid];
        for (int i = 0; i < 128; ++i) acc2 += h1[i] * Wm2[i * 64 + tid];
        h2[tid] = selu_f(acc2);
    }
    __syncthreads();
    if (tid < 64) {
        float p = h2[tid] * Wm3[tid];
        #pragma unroll
        for (int off = 32; off; off >>= 1) p += __shfl_xor(p, off, 64);
        if (tid == 0) out[g] = p + bm3[0];
    }
}

// ---------------- CSR build helpers ----------------
__global__ void count_dst_kernel(const int* __restrict__ dst, int* __restrict__ cnt, int E)
{
    int e = blockIdx.x * 256 + threadIdx.x;
    if (e < E) atomicAdd(&cnt[dst[e]], 1);
}
__global__ void fill_csr_kernel(const int* __restrict__ src, const int* __restrict__ dst,
                                int* __restrict__ cursor, int* __restrict__ colsrc, int E)
{
    int e = blockIdx.x * 256 + threadIdx.x;
    if (e < E) {
        int p = atomicAdd(&cursor[dst[e]], 1);
        colsrc[p] = src[e];
    }
}

// gid is SORTED: build graph ranges directly (replaces count+scan chain).
__global__ void gid_ranges_kernel(const int* __restrict__ gid, int* __restrict__ gptr, int n)
{
    int i = blockIdx.x * 256 + threadIdx.x;
    if (i >= n) return;
    int cur = gid[i];
    int prev = (i == 0) ? -1 : gid[i - 1];
    for (int g = prev + 1; g <= cur; ++g) gptr[g] = i;
    if (i == n - 1)
        for (int g = cur + 1; g <= GG; ++g) gptr[g] = n;
}

// exclusive scan, 1024 elems/block
__global__ __launch_bounds__(256) void scan_blocks_kernel(
    const int* __restrict__ in, int n, int* __restrict__ out, int* __restrict__ partials)
{
    __shared__ int lds[256];
    int tid = threadIdx.x;
    int base = blockIdx.x * 1024 + tid * 4;
    int v0 = (base + 0 < n) ? in[base + 0] : 0;
    int v1 = (base + 1 < n) ? in[base + 1] : 0;
    int v2 = (base + 2 < n) ? in[base + 2] : 0;
    int v3 = (base + 3 < n) ? in[base + 3] : 0;
    int s = v0 + v1 + v2 + v3;
    lds[tid] = s;
    __syncthreads();
    for (int off = 1; off < 256; off <<= 1) {
        int t = (tid >= off) ? lds[tid - off] : 0;
        __syncthreads();
        lds[tid] += t;
        __syncthreads();
    }
    int excl = lds[tid] - s;
    if (base + 0 < n) out[base + 0] = excl;
    if (base + 1 < n) out[base + 1] = excl + v0;
    if (base + 2 < n) out[base + 2] = excl + v0 + v1;
    if (base + 3 < n) out[base + 3] = excl + v0 + v1 + v2;
    if (tid == 255) partials[blockIdx.x] = lds[255];
}

__global__ __launch_bounds__(256) void scan_partials_kernel(int* partials, int nb)
{
    __shared__ int lds[256];
    int tid = threadIdx.x;
    int v = (tid < nb) ? partials[tid] : 0;
    lds[tid] = v;
    __syncthreads();
    for (int off = 1; off < 256; off <<= 1) {
        int t = (tid >= off) ? lds[tid - off] : 0;
        __syncthreads();
        lds[tid] += t;
        __syncthreads();
    }
    int excl = lds[tid] - v;
    if (tid < nb) partials[tid] = excl;
}

__global__ void add_offsets_kernel(int* __restrict__ out, const int* __restrict__ partials, int n)
{
    int i = blockIdx.x * 256 + threadIdx.x;
    if (i < n) out[i] += partials[i >> 10];
}

// ---------------- launch ----------------
extern "C" void kernel_launch(void* const* d_in, const int* in_sizes, int n_in,
                              void* d_out, int out_size, void* d_ws, size_t ws_size,
                              hipStream_t stream)
{
    const float* feats_node  = (const float*)d_in[0];
    const float* feats_graph = (const float*)d_in[1];
    const float* W1  = (const float*)d_in[2];
    const float* al1 = (const float*)d_in[3];
    const float* ar1 = (const float*)d_in[4];
    const float* b1  = (const float*)d_in[5];
    const float* W2  = (const float*)d_in[6];
    const float* al2 = (const float*)d_in[7];
    const float* ar2 = (const float*)d_in[8];
    const float* b2  = (const float*)d_in[9];
    const float* Ws  = (const float*)d_in[10];
    const float* bs  = (const float*)d_in[11];
    const float* Wm1 = (const float*)d_in[12];
    const float* bm1 = (const float*)d_in[13];
    const float* Wm2 = (const float*)d_in[14];
    const float* bm2 = (const float*)d_in[15];
    const float* Wm3 = (const float*)d_in[16];
    const float* bm3 = (const float*)d_in[17];
    const int* src = (const int*)d_in[18];
    const int* dst = (const int*)d_in[19];
    const int* gid = (const int*)d_in[20];
    float* out = (float*)d_out;
    const int E = in_sizes[18];   // 900000

    // workspace carve-up (256B aligned). Total < 231 MB proven footprint.
    char* p = (char*)d_ws;
    auto alloc = [&](size_t bytes) {
        char* r = p;
        p += (bytes + 255) & ~(size_t)255;
        return r;
    };
    u16*   Yh     = (u16*)alloc((size_t)NN * HID * 2);      // Y1 hi; later F2 bf16 (alias)
    u16*   Yl     = (u16*)alloc((size_t)NN * HID * 2);      // Y1 lo
    u16*   Xh     = (u16*)alloc((size_t)NN * HID * 2);      // X1 hi; later X2 bf16 (alias)
    u16*   Xl     = (u16*)alloc((size_t)NN * HID * 2);      // X1 lo
    float* el     = (float*)alloc((size_t)NN * HH * 4);
    float* er     = (float*)alloc((size_t)NN * HH * 4);
    float* wbuf   = (float*)alloc((size_t)E * HH * 4);      // softmax weights
    float* invden = (float*)alloc((size_t)NN * HH * 4);
    int*   cnt    = (int*)alloc((size_t)(NN + 1) * 4);      // reused as cursor
    int*   rowptr = (int*)alloc((size_t)(NN + 1) * 4);
    int*   colsrc = (int*)alloc((size_t)E * 4);
    int*   gptr   = (int*)alloc((size_t)(GG + 1) * 4);
    int*   parts  = (int*)alloc(1024 * 4);
    float* emb    = (float*)alloc((size_t)GG * HID * 4);
    u16*   BT1h   = (u16*)alloc((size_t)HID * INF_ * 2);
    u16*   BT1l   = (u16*)alloc((size_t)HID * INF_ * 2);
    u16*   BT2h   = (u16*)alloc((size_t)HID * HID * 2);
    u16*   BT2l   = (u16*)alloc((size_t)HID * HID * 2);
    float* wal1   = (float*)alloc(INF_ * HH * 4);
    float* war1   = (float*)alloc(INF_ * HH * 4);
    u16*   Fbf2   = Yh;        // alias: Yh/Yl dead after gemm_head
    u16*   Xbf2   = Xh;        // alias: Xh/Xl dead after gemm2 consumed them

    // ---- CSR over dst ----
    hipMemsetAsync(cnt, 0, (size_t)(NN + 1) * 4, stream);
    count_dst_kernel<<<(E + 255) / 256, 256, 0, stream>>>(dst, cnt, E);
    {
        int n = NN + 1, nb = (n + 1023) / 1024;
        scan_blocks_kernel<<<nb, 256, 0, stream>>>(cnt, n, rowptr, parts);
        scan_partials_kernel<<<1, 256, 0, stream>>>(parts, nb);
        add_offsets_kernel<<<(n + 255) / 256, 256, 0, stream>>>(rowptr, parts, n);
    }
    hipMemcpyAsync(cnt, rowptr, (size_t)(NN + 1) * 4, hipMemcpyDeviceToDevice, stream);
    fill_csr_kernel<<<(E + 255) / 256, 256, 0, stream>>>(src, dst, cnt, colsrc, E);

    // ---- graph ranges (node_gid sorted -> direct) ----
    gid_ranges_kernel<<<(NN + 255) / 256, 256, 0, stream>>>(gid, gptr, NN);

    // ---- weight conversions / precomputes ----
    wsplit_kernel<<<(HID * INF_ + 255) / 256, 256, 0, stream>>>(W1, BT1h, BT1l, INF_, 6);
    wsplit_kernel<<<(HID * HID + 255) / 256, 256, 0, stream>>>(W2, BT2h, BT2l, HID, 8);
    walprep_kernel<<<1, 256, 0, stream>>>(W1, al1, ar1, wal1, war1);

    const int nh_blocks = (NN * HH + 255) / 256;

    // ---- GAT layer 1 (reassociated: gather raw feats, then per-head GEMM) ----
    elr1_kernel<<<nh_blocks, 256, 0, stream>>>(feats_node, wal1, war1, el, er);
    edge_softmax_kernel<<<nh_blocks, 256, 0, stream>>>(el, er, rowptr, colsrc, wbuf, invden);
    aggregate_feats_kernel<<<(NN + 3) / 4, 256, 0, stream>>>(feats_node, wbuf, invden,
                                                             rowptr, colsrc, Yh, Yl);
    {
        dim3 hgrid((NN + 127) / 128, HH);
        gemm_head_kernel<<<hgrid, 256, 0, stream>>>(Yh, Yl, BT1h, BT1l, b1, Xh, Xl, NN);
    }

    // ---- GAT layer 2 (LDS-A/global-B GEMM + separate softmax + aggregate) ----
    dim3 ggrid((NN + 127) / 128, HID / 128);
    mfma_gemm_kernel<<<ggrid, 256, 0, stream>>>(
        Xh, Xl, BT2h, BT2l, Fbf2, al2, ar2, el, er, NN, HID);
    edge_softmax_kernel<<<nh_blocks, 256, 0, stream>>>(el, er, rowptr, colsrc, wbuf, invden);
    aggregate_bf16_kernel<<<(NN + 3) / 4, 256, 0, stream>>>(Fbf2, wbuf, invden, rowptr, colsrc,
                                                            b2, Xbf2);

    // ---- readout + MLP ----
    readout_kernel<<<(GG + 3) / 4, 256, 0, stream>>>(Xbf2, Ws, bs, gptr, emb);
    mlp_kernel<<<GG, 128, 0, stream>>>(emb, feats_graph, Wm1, bm1, Wm2, bm2, Wm3, bm3, out);
}

// Round 17
// 590.035 us; speedup vs baseline: 1.0332x; 1.0332x over previous
//
#include <hip/hip_runtime.h>
#include <hip/hip_bf16.h>
#include <math.h>

// Problem constants (fixed by the reference)
#define NN     100000   // nodes
#define GG     2000     // graphs
#define HH     4        // heads
#define DD     64       // per-head dim
#define HID    256      // H*D
#define INF_   64       // in feats
#define EXTRA  8        // graph feats

typedef unsigned short u16;
typedef __attribute__((ext_vector_type(8))) short bf16x8;
typedef __attribute__((ext_vector_type(4))) float f32x4;

__device__ __forceinline__ u16 f2bf(float f) {
    unsigned u = __float_as_uint(f);
    return (u16)((u + 0x7fffu + ((u >> 16) & 1u)) >> 16);
}
__device__ __forceinline__ float bf2f(u16 v) {
    return __uint_as_float(((unsigned)v) << 16);
}

// ---------------- W [K,256] -> transposed hi/lo bf16 [256,K] ----------------
// Row-major transposed (round-15 proven). Rounds 10/11/16 all showed MFMA
// operands must be staged through LDS with coalesced writes — fragment-
// ordered global-direct B regressed (MfmaUtil 19->14.7%).
__global__ __launch_bounds__(256) void wsplit_kernel(
    const float* __restrict__ W, u16* __restrict__ hi, u16* __restrict__ lo,
    int K, int lgK)
{
    int idx = blockIdx.x * 256 + threadIdx.x;   // n*K + k
    if (idx >= 256 * K) return;
    int n = idx >> lgK, k = idx & (K - 1);
    float w = W[k * HID + n];
    u16 h = f2bf(w);
    hi[idx] = h;
    lo[idx] = f2bf(w - bf2f(h));
}

// ---------------- wal/war precompute: wal[d][h] = sum_c W1[d][h*64+c]*al[h][c]
__global__ __launch_bounds__(256) void walprep_kernel(
    const float* __restrict__ W1, const float* __restrict__ al,
    const float* __restrict__ ar, float* __restrict__ wal, float* __restrict__ war)
{
    int tid = threadIdx.x;          // 256 = 64 d x 4 h
    int d = tid >> 2, h = tid & 3;
    const float* wrow = W1 + d * HID + h * DD;
    const float* av = al + h * DD;
    const float* bv = ar + h * DD;
    float s1 = 0.f, s2 = 0.f;
    for (int c = 0; c < DD; ++c) { s1 += wrow[c] * av[c]; s2 += wrow[c] * bv[c]; }
    wal[d * 4 + h] = s1;
    war[d * 4 + h] = s2;
}

// ---------------- el1/er1 from raw feats (reassociated: feats @ wal1) ---------
__global__ __launch_bounds__(256) void elr1_kernel(
    const float* __restrict__ feats, const float* __restrict__ wal,
    const float* __restrict__ war, float* __restrict__ el, float* __restrict__ er)
{
    int idx = blockIdx.x * 256 + threadIdx.x;   // (n,h)
    if (idx >= NN * HH) return;
    int n = idx >> 2, h = idx & 3;
    const float* f = feats + (size_t)n * INF_;
    float s1 = 0.f, s2 = 0.f;
    #pragma unroll 4
    for (int d = 0; d < INF_; d += 4) {
        float4 fv = *reinterpret_cast<const float4*>(f + d);
        s1 += fv.x * wal[(d + 0) * 4 + h] + fv.y * wal[(d + 1) * 4 + h]
            + fv.z * wal[(d + 2) * 4 + h] + fv.w * wal[(d + 3) * 4 + h];
        s2 += fv.x * war[(d + 0) * 4 + h] + fv.y * war[(d + 1) * 4 + h]
            + fv.z * war[(d + 2) * 4 + h] + fv.w * war[(d + 3) * 4 + h];
    }
    el[idx] = s1;
    er[idx] = s2;
}

__device__ __forceinline__ float leaky02(float x) { return x > 0.f ? x : 0.2f * x; }

// ---------------- edge softmax: one thread per (dst-node, head) ---------------
// SEPARATE kernel (round-14 lesson: VALU time is per-wave, not per-active-
// lane; fusing into the wave-per-node aggregate cost 16x more exp work).
__global__ __launch_bounds__(256) void edge_softmax_kernel(
    const float* __restrict__ el, const float* __restrict__ er,
    const int* __restrict__ rowptr, const int* __restrict__ colsrc,
    float* __restrict__ w, float* __restrict__ invden)
{
    int idx = blockIdx.x * 256 + threadIdx.x;   // (t,h)
    if (idx >= NN * HH) return;
    int t = idx >> 2, h = idx & 3;
    int beg = rowptr[t], end = rowptr[t + 1];
    float ert = er[idx];
    float m = -1e30f;
    for (int i = beg; i < end; ++i) {
        int s = colsrc[i];
        m = fmaxf(m, leaky02(el[s * 4 + h] + ert));
    }
    float den = 0.f;
    for (int i = beg; i < end; ++i) {
        int s = colsrc[i];
        float v = expf(leaky02(el[s * 4 + h] + ert) - m);
        w[(size_t)i * 4 + h] = v;
        den += v;
    }
    invden[idx] = 1.f / den;   // deg >= 1 (self-loops), den > 0
}

// ---------------- layer-1 aggregate over RAW feats -> PRE-SPLIT Y1 ------------
__global__ __launch_bounds__(256) void aggregate_feats_kernel(
    const float* __restrict__ feats, const float* __restrict__ w,
    const float* __restrict__ invden, const int* __restrict__ rowptr,
    const int* __restrict__ colsrc, u16* __restrict__ Yh, u16* __restrict__ Yl)
{
    int t = blockIdx.x * 4 + (threadIdx.x >> 6);
    int lane = threadIdx.x & 63;
    if (t >= NN) return;
    int beg = rowptr[t], end = rowptr[t + 1];
    float a0 = 0.f, a1 = 0.f, a2 = 0.f, a3 = 0.f;
    float b0 = 0.f, b1 = 0.f, b2 = 0.f, b3 = 0.f;
    int i = beg;
    for (; i + 1 < end; i += 2) {
        int s0 = colsrc[i], s1 = colsrc[i + 1];
        float4 w0 = *reinterpret_cast<const float4*>(w + (size_t)i * 4);
        float4 w1 = *reinterpret_cast<const float4*>(w + (size_t)(i + 1) * 4);
        float f0 = feats[(size_t)s0 * INF_ + lane];
        float f1 = feats[(size_t)s1 * INF_ + lane];
        a0 += w0.x * f0; a1 += w0.y * f0; a2 += w0.z * f0; a3 += w0.w * f0;
        b0 += w1.x * f1; b1 += w1.y * f1; b2 += w1.z * f1; b3 += w1.w * f1;
    }
    if (i < end) {
        int s0 = colsrc[i];
        float4 w0 = *reinterpret_cast<const float4*>(w + (size_t)i * 4);
        float f0 = feats[(size_t)s0 * INF_ + lane];
        a0 += w0.x * f0; a1 += w0.y * f0; a2 += w0.z * f0; a3 += w0.w * f0;
    }
    float4 inv = *reinterpret_cast<const float4*>(invden + (size_t)t * 4);
    float y0 = (a0 + b0) * inv.x;
    float y1 = (a1 + b1) * inv.y;
    float y2 = (a2 + b2) * inv.z;
    float y3 = (a3 + b3) * inv.w;
    u16* yh = Yh + (size_t)t * HID;
    u16* yl = Yl + (size_t)t * HID;
    u16 h0 = f2bf(y0), h1 = f2bf(y1), h2 = f2bf(y2), h3 = f2bf(y3);
    yh[lane] = h0;        yl[lane] = f2bf(y0 - bf2f(h0));
    yh[64 + lane] = h1;   yl[64 + lane] = f2bf(y1 - bf2f(h1));
    yh[128 + lane] = h2;  yl[128 + lane] = f2bf(y2 - bf2f(h2));
    yh[192 + lane] = h3;  yl[192 + lane] = f2bf(y3 - bf2f(h3));
}

// ---------------- per-head GEMM: X1 = relu(Y1 @ W1 + b1), LDS-staged ----------
__global__ __launch_bounds__(256) void gemm_head_kernel(
    const u16* __restrict__ Yh, const u16* __restrict__ Yl,
    const u16* __restrict__ BThi, const u16* __restrict__ BTlo,
    const float* __restrict__ bias,
    u16* __restrict__ Xh, u16* __restrict__ Xl, int M)
{
    __shared__ __align__(16) u16 Ah[128 * 64];
    __shared__ __align__(16) u16 Al[128 * 64];
    __shared__ __align__(16) u16 Bh[64 * 64];
    __shared__ __align__(16) u16 Bl[64 * 64];
    const int tid  = threadIdx.x;
    const int wave = tid >> 6, lane = tid & 63;
    const int quad = lane >> 4, l15 = lane & 15;
    const int wy = wave >> 1, wx = wave & 1;      // 2x2: 64 rows x 32 cols each
    const int head = blockIdx.y;
    const int r0 = blockIdx.x * 128;
    const int cb = head * DD;                      // this head's Y1 column base

    // ---- stage A: 128 rows x 64 k (hi+lo), thread = (row, half32) ----
    {
        int row = tid >> 1, half = tid & 1;
        int gr = min(r0 + row, M - 1);
        size_t goff = (size_t)gr * HID + cb;
        #pragma unroll
        for (int m = 0; m < 4; ++m) {
            int c = half * 4 + m;                  // global chunk (8 u16)
            int cs = c ^ (row & 7);                // swizzled LDS chunk
            *reinterpret_cast<bf16x8*>(&Ah[row * 64 + cs * 8]) =
                *reinterpret_cast<const bf16x8*>(Yh + goff + c * 8);
            *reinterpret_cast<bf16x8*>(&Al[row * 64 + cs * 8]) =
                *reinterpret_cast<const bf16x8*>(Yl + goff + c * 8);
        }
        // B: 64 rows (out dims) x 64 k, thread = (d = tid&63, seg = tid>>6)
        int d = tid & 63, seg = tid >> 6;
        size_t boff = (size_t)(head * DD + d) * 64;
        #pragma unroll
        for (int m = 0; m < 2; ++m) {
            int c = seg * 2 + m;
            int cs = c ^ (d & 7);
            *reinterpret_cast<bf16x8*>(&Bh[d * 64 + cs * 8]) =
                *reinterpret_cast<const bf16x8*>(BThi + boff + c * 8);
            *reinterpret_cast<bf16x8*>(&Bl[d * 64 + cs * 8]) =
                *reinterpret_cast<const bf16x8*>(BTlo + boff + c * 8);
        }
    }
    __syncthreads();

    f32x4 acc[4][2];
    #pragma unroll
    for (int i = 0; i < 4; ++i)
        #pragma unroll
        for (int j = 0; j < 2; ++j)
            acc[i][j] = (f32x4){0.f, 0.f, 0.f, 0.f};

    #pragma unroll
    for (int k0 = 0; k0 < 64; k0 += 32) {
        bf16x8 afh[4], afl[4], bfh[2], bfl[2];
        #pragma unroll
        for (int i = 0; i < 4; ++i) {
            int Ra = wy * 64 + i * 16 + l15;
            int c = (k0 >> 3) + quad;
            int cs = c ^ (Ra & 7);
            afh[i] = *reinterpret_cast<const bf16x8*>(&Ah[Ra * 64 + cs * 8]);
            afl[i] = *reinterpret_cast<const bf16x8*>(&Al[Ra * 64 + cs * 8]);
        }
        #pragma unroll
        for (int j = 0; j < 2; ++j) {
            int Rb = wx * 32 + j * 16 + l15;
            int c = (k0 >> 3) + quad;
            int cs = c ^ (Rb & 7);
            bfh[j] = *reinterpret_cast<const bf16x8*>(&Bh[Rb * 64 + cs * 8]);
            bfl[j] = *reinterpret_cast<const bf16x8*>(&Bl[Rb * 64 + cs * 8]);
        }
        #pragma unroll
        for (int i = 0; i < 4; ++i)
            #pragma unroll
            for (int j = 0; j < 2; ++j) {
                acc[i][j] = __builtin_amdgcn_mfma_f32_16x16x32_bf16(afh[i], bfh[j], acc[i][j], 0, 0, 0);
                acc[i][j] = __builtin_amdgcn_mfma_f32_16x16x32_bf16(afl[i], bfh[j], acc[i][j], 0, 0, 0);
                acc[i][j] = __builtin_amdgcn_mfma_f32_16x16x32_bf16(afh[i], bfl[j], acc[i][j], 0, 0, 0);
            }
    }

    // ---- epilogue: bias + relu + split store. col = cb + wx*32 + j*16 + l15
    float bv[2];
    #pragma unroll
    for (int j = 0; j < 2; ++j) bv[j] = bias[cb + wx * 32 + j * 16 + l15];
    #pragma unroll
    for (int i = 0; i < 4; ++i)
        #pragma unroll
        for (int rr = 0; rr < 4; ++rr) {
            int grow = r0 + wy * 64 + i * 16 + quad * 4 + rr;
            if (grow < M) {
                size_t base = (size_t)grow * HID + cb + wx * 32 + l15;
                #pragma unroll
                for (int j = 0; j < 2; ++j) {
                    float x = fmaxf(acc[i][j][rr] + bv[j], 0.f);
                    u16 h = f2bf(x);
                    Xh[base + j * 16] = h;
                    Xl[base + j * 16] = f2bf(x - bf2f(h));
                }
            }
        }
}

// ---------------- MFMA GEMM (layer 2): pre-split A, swizzled LDS, el/er epi ---
// Both operands through swizzled LDS ((r>>1)&3 -> uniform 2-way banks).
// Round-15-proven form; global-direct B (r16) and LDS-free (r10) both regressed.
__global__ __launch_bounds__(256) void mfma_gemm_kernel(
    const u16* __restrict__ Ahg, const u16* __restrict__ Alg,
    const u16* __restrict__ BThi, const u16* __restrict__ BTlo,
    u16* __restrict__ Cb,
    const float* __restrict__ al, const float* __restrict__ ar,
    float* __restrict__ el, float* __restrict__ er, int M, int K)
{
    __shared__ __align__(16) u16 Ah[128 * 32];
    __shared__ __align__(16) u16 Al[128 * 32];
    __shared__ __align__(16) u16 Bh[128 * 32];
    __shared__ __align__(16) u16 Bl[128 * 32];
    const int tid  = threadIdx.x;
    const int wave = tid >> 6, lane = tid & 63;
    const int quad = lane >> 4, l15 = lane & 15;
    const int wy = wave >> 1, wx = wave & 1;
    const int r0 = blockIdx.x * 128, c0 = blockIdx.y * 128;
    const int sr = tid >> 2, sseg = tid & 3;

    f32x4 acc[4][4];
    #pragma unroll
    for (int i = 0; i < 4; ++i)
        #pragma unroll
        for (int j = 0; j < 4; ++j)
            acc[i][j] = (f32x4){0.f, 0.f, 0.f, 0.f};

    for (int k0 = 0; k0 < K; k0 += 32) {
        #pragma unroll
        for (int half = 0; half < 2; ++half) {
            int r = sr + half * 64;
            int cs = (sseg ^ ((r >> 1) & 3)) * 8;  // swizzled LDS chunk offset
            int gr = min(r0 + r, M - 1);
            size_t aoff = (size_t)gr * K + k0 + sseg * 8;
            *reinterpret_cast<bf16x8*>(&Ah[r * 32 + cs]) =
                *reinterpret_cast<const bf16x8*>(Ahg + aoff);
            *reinterpret_cast<bf16x8*>(&Al[r * 32 + cs]) =
                *reinterpret_cast<const bf16x8*>(Alg + aoff);
            int gc = c0 + r;   // < 256 always
            size_t boff = (size_t)gc * K + k0 + sseg * 8;
            *reinterpret_cast<bf16x8*>(&Bh[r * 32 + cs]) =
                *reinterpret_cast<const bf16x8*>(BThi + boff);
            *reinterpret_cast<bf16x8*>(&Bl[r * 32 + cs]) =
                *reinterpret_cast<const bf16x8*>(BTlo + boff);
        }
        __syncthreads();
        bf16x8 afh[4], afl[4], bfh[4], bfl[4];
        #pragma unroll
        for (int i = 0; i < 4; ++i) {
            int Ra = wy * 64 + i * 16 + l15;
            int off = Ra * 32 + (quad ^ ((Ra >> 1) & 3)) * 8;
            afh[i] = *reinterpret_cast<const bf16x8*>(&Ah[off]);
            afl[i] = *reinterpret_cast<const bf16x8*>(&Al[off]);
        }
        #pragma unroll
        for (int j = 0; j < 4; ++j) {
            int Rb = wx * 64 + j * 16 + l15;
            int off = Rb * 32 + (quad ^ ((Rb >> 1) & 3)) * 8;
            bfh[j] = *reinterpret_cast<const bf16x8*>(&Bh[off]);
            bfl[j] = *reinterpret_cast<const bf16x8*>(&Bl[off]);
        }
        #pragma unroll
        for (int i = 0; i < 4; ++i)
            #pragma unroll
            for (int j = 0; j < 4; ++j) {
                acc[i][j] = __builtin_amdgcn_mfma_f32_16x16x32_bf16(afh[i], bfh[j], acc[i][j], 0, 0, 0);
                acc[i][j] = __builtin_amdgcn_mfma_f32_16x16x32_bf16(afl[i], bfh[j], acc[i][j], 0, 0, 0);
                acc[i][j] = __builtin_amdgcn_mfma_f32_16x16x32_bf16(afh[i], bfl[j], acc[i][j], 0, 0, 0);
            }
        __syncthreads();
    }

    // ---- C store (bf16). C/D layout: col = l15, row = quad*4 + rr ----
    #pragma unroll
    for (int i = 0; i < 4; ++i)
        #pragma unroll
        for (int rr = 0; rr < 4; ++rr) {
            int grow = r0 + wy * 64 + i * 16 + quad * 4 + rr;
            if (grow < M) {
                u16* crow = Cb + (size_t)grow * HID + c0 + wx * 64 + l15;
                #pragma unroll
                for (int j = 0; j < 4; ++j) crow[j * 16] = f2bf(acc[i][j][rr]);
            }
        }

    // ---- fused el/er from f32 accumulators (one head per wave) ----
    const int h = blockIdx.y * 2 + wx;
    float alf[4], arf[4];
    #pragma unroll
    for (int j = 0; j < 4; ++j) {
        alf[j] = al[h * DD + j * 16 + l15];
        arf[j] = ar[h * DD + j * 16 + l15];
    }
    #pragma unroll
    for (int i = 0; i < 4; ++i)
        #pragma unroll
        for (int rr = 0; rr < 4; ++rr) {
            float sl = acc[i][0][rr] * alf[0] + acc[i][1][rr] * alf[1]
                     + acc[i][2][rr] * alf[2] + acc[i][3][rr] * alf[3];
            float sr_ = acc[i][0][rr] * arf[0] + acc[i][1][rr] * arf[1]
                      + acc[i][2][rr] * arf[2] + acc[i][3][rr] * arf[3];
            #pragma unroll
            for (int off = 1; off < 16; off <<= 1) {
                sl  += __shfl_xor(sl, off, 64);
                sr_ += __shfl_xor(sr_, off, 64);
            }
            if (l15 == 0) {
                int grow = r0 + wy * 64 + i * 16 + quad * 4 + rr;
                if (grow < M) {
                    el[grow * 4 + h] = sl;
                    er[grow * 4 + h] = sr_;
                }
            }
        }
}

// ---------------- layer-2 aggregate: bf16 gather, 4-deep unroll ---------------
// 4 independent accumulators to raise memory-level parallelism on the
// colsrc->row-gather dependent chain (44% HBM, latency-limited suspicion).
// Final pairwise sum reassociates f32 adds only (~1e-7 rel, invisible).
__global__ __launch_bounds__(256) void aggregate_bf16_kernel(
    const u16* __restrict__ F, const float* __restrict__ w,
    const float* __restrict__ invden, const int* __restrict__ rowptr,
    const int* __restrict__ colsrc, const float* __restrict__ bias,
    u16* __restrict__ out)
{
    int t = blockIdx.x * 4 + (threadIdx.x >> 6);
    int lane = threadIdx.x & 63;
    if (t >= NN) return;
    int beg = rowptr[t], end = rowptr[t + 1];
    const int h = lane >> 4;
    float4 acc0 = make_float4(0.f, 0.f, 0.f, 0.f);
    float4 acc1 = make_float4(0.f, 0.f, 0.f, 0.f);
    float4 acc2 = make_float4(0.f, 0.f, 0.f, 0.f);
    float4 acc3 = make_float4(0.f, 0.f, 0.f, 0.f);
    int i = beg;
    for (; i + 3 < end; i += 4) {
        int s0 = colsrc[i], s1 = colsrc[i + 1], s2 = colsrc[i + 2], s3 = colsrc[i + 3];
        float w0 = w[(size_t)i * 4 + h];
        float w1 = w[(size_t)(i + 1) * 4 + h];
        float w2 = w[(size_t)(i + 2) * 4 + h];
        float w3 = w[(size_t)(i + 3) * 4 + h];
        ushort4 f0 = *reinterpret_cast<const ushort4*>(F + (size_t)s0 * HID + 4 * lane);
        ushort4 f1 = *reinterpret_cast<const ushort4*>(F + (size_t)s1 * HID + 4 * lane);
        ushort4 f2 = *reinterpret_cast<const ushort4*>(F + (size_t)s2 * HID + 4 * lane);
        ushort4 f3 = *reinterpret_cast<const ushort4*>(F + (size_t)s3 * HID + 4 * lane);
        acc0.x += w0 * bf2f(f0.x); acc0.y += w0 * bf2f(f0.y);
        acc0.z += w0 * bf2f(f0.z); acc0.w += w0 * bf2f(f0.w);
        acc1.x += w1 * bf2f(f1.x); acc1.y += w1 * bf2f(f1.y);
        acc1.z += w1 * bf2f(f1.z); acc1.w += w1 * bf2f(f1.w);
        acc2.x += w2 * bf2f(f2.x); acc2.y += w2 * bf2f(f2.y);
        acc2.z += w2 * bf2f(f2.z); acc2.w += w2 * bf2f(f2.w);
        acc3.x += w3 * bf2f(f3.x); acc3.y += w3 * bf2f(f3.y);
        acc3.z += w3 * bf2f(f3.z); acc3.w += w3 * bf2f(f3.w);
    }
    for (; i < end; ++i) {
        int s0 = colsrc[i];
        float w0 = w[(size_t)i * 4 + h];
        ushort4 f0 = *reinterpret_cast<const ushort4*>(F + (size_t)s0 * HID + 4 * lane);
        acc0.x += w0 * bf2f(f0.x); acc0.y += w0 * bf2f(f0.y);
        acc0.z += w0 * bf2f(f0.z); acc0.w += w0 * bf2f(f0.w);
    }
    float inv = invden[t * 4 + h];
    float4 bv = *reinterpret_cast<const float4*>(bias + 4 * lane);
    ushort4 r;
    r.x = f2bf(fmaxf(((acc0.x + acc1.x) + (acc2.x + acc3.x)) * inv + bv.x, 0.f));
    r.y = f2bf(fmaxf(((acc0.y + acc1.y) + (acc2.y + acc3.y)) * inv + bv.y, 0.f));
    r.z = f2bf(fmaxf(((acc0.z + acc1.z) + (acc2.z + acc3.z)) * inv + bv.z, 0.f));
    r.w = f2bf(fmaxf(((acc0.w + acc1.w) + (acc2.w + acc3.w)) * inv + bv.w, 0.f));
    *reinterpret_cast<ushort4*>(out + (size_t)t * HID + 4 * lane) = r;
}

// ---------------- weighted-average readout (bf16 X): one wave per graph -------
__global__ __launch_bounds__(256) void readout_kernel(
    const u16* __restrict__ X, const float* __restrict__ Ws,
    const float* __restrict__ bs, const int* __restrict__ gptr,
    float* __restrict__ emb)
{
    int g = blockIdx.x * 4 + (threadIdx.x >> 6);
    int lane = threadIdx.x & 63;
    if (g >= GG) return;
    int beg = gptr[g], end = gptr[g + 1];
    float4 wv = *reinterpret_cast<const float4*>(Ws + 4 * lane);
    float b = bs[0];
    float4 acc = make_float4(0.f, 0.f, 0.f, 0.f);
    float wsum = 0.f;
    for (int n = beg; n < end; ++n) {
        ushort4 xv = *reinterpret_cast<const ushort4*>(X + (size_t)n * HID + 4 * lane);
        float x0 = bf2f(xv.x), x1 = bf2f(xv.y), x2 = bf2f(xv.z), x3 = bf2f(xv.w);
        float p = x0 * wv.x + x1 * wv.y + x2 * wv.z + x3 * wv.w;
        #pragma unroll
        for (int off = 32; off; off >>= 1) p += __shfl_xor(p, off, 64);
        float w = 1.f / (1.f + expf(-(p + b)));
        wsum += w;
        acc.x += w * x0; acc.y += w * x1; acc.z += w * x2; acc.w += w * x3;
    }
    float inv = (wsum == 0.f) ? 1.f : wsum;
    float4 e;
    e.x = acc.x / inv; e.y = acc.y / inv; e.z = acc.z / inv; e.w = acc.w / inv;
    *reinterpret_cast<float4*>(emb + (size_t)g * HID + 4 * lane) = e;
}

__device__ __forceinline__ float selu_f(float x)
{
    const float scale = 1.0507009873554805f, alpha = 1.6732632423543772f;
    return scale * (x > 0.f ? x : alpha * expm1f(x));
}

// ---------------- MLP head: one block (128 thr) per graph ----------------
__global__ __launch_bounds__(128) void mlp_kernel(
    const float* __restrict__ emb, const float* __restrict__ fg,
    const float* __restrict__ Wm1, const float* __restrict__ bm1,
    const float* __restrict__ Wm2, const float* __restrict__ bm2,
    const float* __restrict__ Wm3, const float* __restrict__ bm3,
    float* __restrict__ out)
{
    int g = blockIdx.x;
    __shared__ float h[HID + EXTRA];
    __shared__ float h1[128];
    __shared__ float h2[64];
    int tid = threadIdx.x;
    h[tid] = emb[(size_t)g * HID + tid];
    h[128 + tid] = emb[(size_t)g * HID + 128 + tid];
    if (tid < EXTRA) h[HID + tid] = fg[(size_t)g * EXTRA + tid];
    __syncthreads();
    float acc = bm1[tid];
    for (int i = 0; i < HID + EXTRA; ++i) acc += h[i] * Wm1[i * 128 + tid];
    h1[tid] = selu_f(acc);
    __syncthreads();
    if (tid < 64) {
        float acc2 = bm2[tid];
        for (int i = 0; i < 128; ++i) acc2 += h1[i] * Wm2[i * 64 + tid];
        h2[tid] = selu_f(acc2);
    }
    __syncthreads();
    if (tid < 64) {
        float p = h2[tid] * Wm3[tid];
        #pragma unroll
        for (int off = 32; off; off >>= 1) p += __shfl_xor(p, off, 64);
        if (tid == 0) out[g] = p + bm3[0];
    }
}

// ---------------- CSR build helpers ----------------
__global__ void count_dst_kernel(const int* __restrict__ dst, int* __restrict__ cnt, int E)
{
    int e = blockIdx.x * 256 + threadIdx.x;
    if (e < E) atomicAdd(&cnt[dst[e]], 1);
}
__global__ void fill_csr_kernel(const int* __restrict__ src, const int* __restrict__ dst,
                                int* __restrict__ cursor, int* __restrict__ colsrc, int E)
{
    int e = blockIdx.x * 256 + threadIdx.x;
    if (e < E) {
        int p = atomicAdd(&cursor[dst[e]], 1);
        colsrc[p] = src[e];
    }
}

// gid is SORTED: build graph ranges directly (replaces count+scan chain).
__global__ void gid_ranges_kernel(const int* __restrict__ gid, int* __restrict__ gptr, int n)
{
    int i = blockIdx.x * 256 + threadIdx.x;
    if (i >= n) return;
    int cur = gid[i];
    int prev = (i == 0) ? -1 : gid[i - 1];
    for (int g = prev + 1; g <= cur; ++g) gptr[g] = i;
    if (i == n - 1)
        for (int g = cur + 1; g <= GG; ++g) gptr[g] = n;
}

// exclusive scan, 1024 elems/block
__global__ __launch_bounds__(256) void scan_blocks_kernel(
    const int* __restrict__ in, int n, int* __restrict__ out, int* __restrict__ partials)
{
    __shared__ int lds[256];
    int tid = threadIdx.x;
    int base = blockIdx.x * 1024 + tid * 4;
    int v0 = (base + 0 < n) ? in[base + 0] : 0;
    int v1 = (base + 1 < n) ? in[base + 1] : 0;
    int v2 = (base + 2 < n) ? in[base + 2] : 0;
    int v3 = (base + 3 < n) ? in[base + 3] : 0;
    int s = v0 + v1 + v2 + v3;
    lds[tid] = s;
    __syncthreads();
    for (int off = 1; off < 256; off <<= 1) {
        int t = (tid >= off) ? lds[tid - off] : 0;
        __syncthreads();
        lds[tid] += t;
        __syncthreads();
    }
    int excl = lds[tid] - s;
    if (base + 0 < n) out[base + 0] = excl;
    if (base + 1 < n) out[base + 1] = excl + v0;
    if (base + 2 < n) out[base + 2] = excl + v0 + v1;
    if (base + 3 < n) out[base + 3] = excl + v0 + v1 + v2;
    if (tid == 255) partials[blockIdx.x] = lds[255];
}

__global__ __launch_bounds__(256) void scan_partials_kernel(int* partials, int nb)
{
    __shared__ int lds[256];
    int tid = threadIdx.x;
    int v = (tid < nb) ? partials[tid] : 0;
    lds[tid] = v;
    __syncthreads();
    for (int off = 1; off < 256; off <<= 1) {
        int t = (tid >= off) ? lds[tid - off] : 0;
        __syncthreads();
        lds[tid] += t;
        __syncthreads();
    }
    int excl = lds[tid] - v;
    if (tid < nb) partials[tid] = excl;
}

__global__ void add_offsets_kernel(int* __restrict__ out, const int* __restrict__ partials, int n)
{
    int i = blockIdx.x * 256 + threadIdx.x;
    if (i < n) out[i] += partials[i >> 10];
}

// ---------------- launch ----------------
extern "C" void kernel_launch(void* const* d_in, const int* in_sizes, int n_in,
                              void* d_out, int out_size, void* d_ws, size_t ws_size,
                              hipStream_t stream)
{
    const float* feats_node  = (const float*)d_in[0];
    const float* feats_graph = (const float*)d_in[1];
    const float* W1  = (const float*)d_in[2];
    const float* al1 = (const float*)d_in[3];
    const float* ar1 = (const float*)d_in[4];
    const float* b1  = (const float*)d_in[5];
    const float* W2  = (const float*)d_in[6];
    const float* al2 = (const float*)d_in[7];
    const float* ar2 = (const float*)d_in[8];
    const float* b2  = (const float*)d_in[9];
    const float* Ws  = (const float*)d_in[10];
    const float* bs  = (const float*)d_in[11];
    const float* Wm1 = (const float*)d_in[12];
    const float* bm1 = (const float*)d_in[13];
    const float* Wm2 = (const float*)d_in[14];
    const float* bm2 = (const float*)d_in[15];
    const float* Wm3 = (const float*)d_in[16];
    const float* bm3 = (const float*)d_in[17];
    const int* src = (const int*)d_in[18];
    const int* dst = (const int*)d_in[19];
    const int* gid = (const int*)d_in[20];
    float* out = (float*)d_out;
    const int E = in_sizes[18];   // 900000

    // workspace carve-up (256B aligned). Total < 231 MB proven footprint.
    char* p = (char*)d_ws;
    auto alloc = [&](size_t bytes) {
        char* r = p;
        p += (bytes + 255) & ~(size_t)255;
        return r;
    };
    u16*   Yh     = (u16*)alloc((size_t)NN * HID * 2);      // Y1 hi; later F2 bf16 (alias)
    u16*   Yl     = (u16*)alloc((size_t)NN * HID * 2);      // Y1 lo
    u16*   Xh     = (u16*)alloc((size_t)NN * HID * 2);      // X1 hi; later X2 bf16 (alias)
    u16*   Xl     = (u16*)alloc((size_t)NN * HID * 2);      // X1 lo
    float* el     = (float*)alloc((size_t)NN * HH * 4);
    float* er     = (float*)alloc((size_t)NN * HH * 4);
    float* wbuf   = (float*)alloc((size_t)E * HH * 4);      // softmax weights
    float* invden = (float*)alloc((size_t)NN * HH * 4);
    int*   cnt    = (int*)alloc((size_t)(NN + 1) * 4);      // reused as cursor
    int*   rowptr = (int*)alloc((size_t)(NN + 1) * 4);
    int*   colsrc = (int*)alloc((size_t)E * 4);
    int*   gptr   = (int*)alloc((size_t)(GG + 1) * 4);
    int*   parts  = (int*)alloc(1024 * 4);
    float* emb    = (float*)alloc((size_t)GG * HID * 4);
    u16*   BT1h   = (u16*)alloc((size_t)HID * INF_ * 2);
    u16*   BT1l   = (u16*)alloc((size_t)HID * INF_ * 2);
    u16*   BT2h   = (u16*)alloc((size_t)HID * HID * 2);
    u16*   BT2l   = (u16*)alloc((size_t)HID * HID * 2);
    float* wal1   = (float*)alloc(INF_ * HH * 4);
    float* war1   = (float*)alloc(INF_ * HH * 4);
    u16*   Fbf2   = Yh;        // alias: Yh/Yl dead after gemm_head
    u16*   Xbf2   = Xh;        // alias: Xh/Xl dead after gemm2 consumed them

    // ---- CSR over dst ----
    hipMemsetAsync(cnt, 0, (size_t)(NN + 1) * 4, stream);
    count_dst_kernel<<<(E + 255) / 256, 256, 0, stream>>>(dst, cnt, E);
    {
        int n = NN + 1, nb = (n + 1023) / 1024;
        scan_blocks_kernel<<<nb, 256, 0, stream>>>(cnt, n, rowptr, parts);
        scan_partials_kernel<<<1, 256, 0, stream>>>(parts, nb);
        add_offsets_kernel<<<(n + 255) / 256, 256, 0, stream>>>(rowptr, parts, n);
    }
    hipMemcpyAsync(cnt, rowptr, (size_t)(NN + 1) * 4, hipMemcpyDeviceToDevice, stream);
    fill_csr_kernel<<<(E + 255) / 256, 256, 0, stream>>>(src, dst, cnt, colsrc, E);

    // ---- graph ranges (node_gid sorted -> direct) ----
    gid_ranges_kernel<<<(NN + 255) / 256, 256, 0, stream>>>(gid, gptr, NN);

    // ---- weight conversions / precomputes ----
    wsplit_kernel<<<(HID * INF_ + 255) / 256, 256, 0, stream>>>(W1, BT1h, BT1l, INF_, 6);
    wsplit_kernel<<<(HID * HID + 255) / 256, 256, 0, stream>>>(W2, BT2h, BT2l, HID, 8);
    walprep_kernel<<<1, 256, 0, stream>>>(W1, al1, ar1, wal1, war1);

    const int nh_blocks = (NN * HH + 255) / 256;

    // ---- GAT layer 1 (reassociated: gather raw feats, then per-head GEMM) ----
    elr1_kernel<<<nh_blocks, 256, 0, stream>>>(feats_node, wal1, war1, el, er);
    edge_softmax_kernel<<<nh_blocks, 256, 0, stream>>>(el, er, rowptr, colsrc, wbuf, invden);
    aggregate_feats_kernel<<<(NN + 3) / 4, 256, 0, stream>>>(feats_node, wbuf, invden,
                                                             rowptr, colsrc, Yh, Yl);
    {
        dim3 hgrid((NN + 127) / 128, HH);
        gemm_head_kernel<<<hgrid, 256, 0, stream>>>(Yh, Yl, BT1h, BT1l, b1, Xh, Xl, NN);
    }

    // ---- GAT layer 2 (swizzled-LDS GEMM + separate softmax + aggregate) ------
    dim3 ggrid((NN + 127) / 128, HID / 128);
    mfma_gemm_kernel<<<ggrid, 256, 0, stream>>>(
        Xh, Xl, BT2h, BT2l, Fbf2, al2, ar2, el, er, NN, HID);
    edge_softmax_kernel<<<nh_blocks, 256, 0, stream>>>(el, er, rowptr, colsrc, wbuf, invden);
    aggregate_bf16_kernel<<<(NN + 3) / 4, 256, 0, stream>>>(Fbf2, wbuf, invden, rowptr, colsrc,
                                                            b2, Xbf2);

    // ---- readout + MLP ----
    readout_kernel<<<(GG + 3) / 4, 256, 0, stream>>>(Xbf2, Ws, bs, gptr, emb);
    mlp_kernel<<<GG, 128, 0, stream>>>(emb, feats_graph, Wm1, bm1, Wm2, bm2, Wm3, bm3, out);
}